// Round 1
// baseline (4179.895 us; speedup 1.0000x reference)
//
#include <hip/hip_runtime.h>
#include <math.h>

#define NMAPS 16
#define DIN 512
#define DOUT 128
#define QD 64
#define NBATCH 256

__device__ __forceinline__ float waveSum(float v) {
#pragma unroll
  for (int off = 32; off > 0; off >>= 1) v += __shfl_xor(v, off, 64);
  return v;
}

// One block per output matrix (m,b). Phase 1: Y = W_m @ X_b into LDS.
// Phase 2: LAPACK-convention Householder QR (sgeqr2) + back-accumulation
// (sorg2r) in LDS. Phase 3: write Q.
__global__ __launch_bounds__(256, 2) void frmap_qr(const float* __restrict__ X,
                                                   const float* __restrict__ W,
                                                   float* __restrict__ out) {
  __shared__ float Ys[DOUT * 65];   // 128 x 64, padded stride 65
  __shared__ float Tau[QD];
  __shared__ float P[4 * QD];       // 4-way row-split partial dots
  __shared__ float Wk[QD];          // per-column w = tau * v^T A[:,k]
  __shared__ float Pred[4];         // per-wave norm partials
  __shared__ float Sc[2];           // broadcast scalars (inv scale)

  const int tid = threadIdx.x;
  const int c = tid & 63;           // column 0..63
  const int g = tid >> 6;           // wave / row-group 0..3
  const int bid = blockIdx.x;       // m*256 + b  (matches Y.reshape(m*b,...))
  const int m = bid >> 8;
  const int b = bid & 255;

  const float* Xb = X + (size_t)b * (DIN * QD);
  const float* Wm = W + (size_t)m * (DOUT * DIN);
  const int rbase = __builtin_amdgcn_readfirstlane(g * 32);  // wave-uniform row panel

  // ---------------- Phase 1: GEMM  Y[o][q] = sum_i W[m][o][i] * X[b][i][q]
  float acc[32];
#pragma unroll
  for (int i = 0; i < 32; ++i) acc[i] = 0.f;

  for (int kc = 0; kc < DIN; kc += 64) {
    float xv[64];
#pragma unroll
    for (int k = 0; k < 64; ++k) xv[k] = Xb[(kc + k) * QD + c];  // coalesced across lanes
#pragma unroll
    for (int rr = 0; rr < 32; ++rr) {
      const float* Wr = Wm + (rbase + rr) * DIN + kc;  // wave-uniform address
      float a = acc[rr];
#pragma unroll
      for (int k4 = 0; k4 < 16; ++k4) {
        float4 w4 = *(const float4*)(Wr + k4 * 4);
        a = fmaf(w4.x, xv[k4 * 4 + 0], a);
        a = fmaf(w4.y, xv[k4 * 4 + 1], a);
        a = fmaf(w4.z, xv[k4 * 4 + 2], a);
        a = fmaf(w4.w, xv[k4 * 4 + 3], a);
      }
      acc[rr] = a;
    }
  }
#pragma unroll
  for (int rr = 0; rr < 32; ++rr) Ys[(rbase + rr) * 65 + c] = acc[rr];
  __syncthreads();

  // ---------------- Phase 2a: sgeqr2 (Householder factorization, LAPACK order)
  for (int j = 0; j < QD; ++j) {
    // norm^2 of A[j+1:128, j]; one element per thread (len <= 127 < 256)
    int r = j + 1 + tid;
    float s = 0.f;
    if (r < DOUT) { float v = Ys[r * 65 + j]; s = v * v; }
    s = waveSum(s);
    if (c == 0) Pred[g] = s;
    __syncthreads();
    if (tid == 0) {
      float xn2 = Pred[0] + Pred[1] + Pred[2] + Pred[3];
      float alpha = Ys[j * 65 + j];
      float tau, invs;
      if (xn2 == 0.f) { tau = 0.f; invs = 0.f; }  // H = I
      else {
        float mag = sqrtf(alpha * alpha + xn2);
        float beta = (alpha >= 0.f) ? -mag : mag;   // slarfg sign convention
        tau = (beta - alpha) / beta;
        invs = 1.f / (alpha - beta);
      }
      Tau[j] = tau; Sc[0] = invs;
    }
    __syncthreads();
    float invs = Sc[0];
    if (r < DOUT) Ys[r * 65 + j] *= invs;   // v = x / (alpha - beta); v_j = 1 implicit
    __syncthreads();
    // larf: A[j:,k] -= tau * v * (v^T A[j:,k]) for k > j
    float tau = Tau[j];
    float p = 0.f;
    if (c > j) {
      for (int r2 = j + g; r2 < DOUT; r2 += 4) {
        float v = (r2 == j) ? 1.f : Ys[r2 * 65 + j];
        p = fmaf(v, Ys[r2 * 65 + c], p);
      }
      P[g * QD + c] = p;
    }
    __syncthreads();
    if (g == 0 && c > j)
      Wk[c] = tau * (P[c] + P[QD + c] + P[2 * QD + c] + P[3 * QD + c]);
    __syncthreads();
    if (c > j) {
      float w = Wk[c];
      for (int r2 = j + g; r2 < DOUT; r2 += 4) {
        float v = (r2 == j) ? 1.f : Ys[r2 * 65 + j];
        Ys[r2 * 65 + c] -= w * v;
      }
    }
    __syncthreads();
  }

  // ---------------- Phase 2b: sorg2r (form Q in place, reverse order)
  for (int i = QD - 1; i >= 0; --i) {
    float tau = Tau[i];
    // larf on trailing columns k > i (which already hold Q-columns), rows i..127
    float p = 0.f;
    if (c > i) {
      for (int r2 = i + g; r2 < DOUT; r2 += 4) {
        float v = (r2 == i) ? 1.f : Ys[r2 * 65 + i];
        p = fmaf(v, Ys[r2 * 65 + c], p);
      }
      P[g * QD + c] = p;
    }
    __syncthreads();
    if (g == 0 && c > i)
      Wk[c] = tau * (P[c] + P[QD + c] + P[2 * QD + c] + P[3 * QD + c]);
    __syncthreads();
    if (c > i) {
      float w = Wk[c];
      for (int r2 = i + g; r2 < DOUT; r2 += 4) {
        float v = (r2 == i) ? 1.f : Ys[r2 * 65 + i];
        Ys[r2 * 65 + c] -= w * v;
      }
    }
    __syncthreads();
    // column i: rows<i -> 0, row i -> 1-tau, rows>i -> -tau*v
    if (tid < DOUT) {
      float val = Ys[tid * 65 + i];
      float nv;
      if (tid == i)       nv = 1.f - tau;
      else if (tid < i)   nv = 0.f;
      else                nv = -tau * val;
      Ys[tid * 65 + i] = nv;
    }
    __syncthreads();
  }

  // ---------------- Phase 3: write Q, coalesced
  float* O = out + (size_t)bid * (DOUT * QD);
#pragma unroll
  for (int rr = 0; rr < 32; ++rr)
    O[(rbase + rr) * QD + c] = Ys[(rbase + rr) * 65 + c];
}

extern "C" void kernel_launch(void* const* d_in, const int* in_sizes, int n_in,
                              void* d_out, int out_size, void* d_ws, size_t ws_size,
                              hipStream_t stream) {
  const float* X = (const float*)d_in[0];   // (256, 512, 64) fp32
  const float* W = (const float*)d_in[1];   // (16, 128, 512) fp32
  float* out = (float*)d_out;               // (4096, 128, 64) fp32
  frmap_qr<<<NMAPS * NBATCH, 256, 0, stream>>>(X, W, out);
}

// Round 2
// 3136.800 us; speedup vs baseline: 1.3325x; 1.3325x over previous
//
#include <hip/hip_runtime.h>
#include <math.h>

#define NMAPS 16
#define DIN 512
#define DOUT 128
#define QD 64
#define NB 256

// One block (256 thr = 4 waves) per output matrix (m,b).
// Thread (c,g) owns rows r = g + 4k (k=0..31) of column c, in registers a[32].
// Phase 1: GEMM into regs. Phase 2: sgeqr2 + sorg2r with LDS only for
// broadcast (v, tau, partial dots). Phase 3: coalesced store.
__global__ __launch_bounds__(256, 4) void frmap_qr(const float* __restrict__ X,
                                                   const float* __restrict__ W,
                                                   float* __restrict__ out) {
  __shared__ float Vbuf[2][DOUT];  // Householder vector broadcast (double-buffered)
  __shared__ float P[4][QD];       // per-wave partial dots
  __shared__ float Wk[QD];         // tau * v^T A[:,c]
  __shared__ float Pred[4];        // norm^2 partials
  __shared__ float Tau[QD];
  __shared__ float Sc[2];          // [0]=invs, [1]=alpha

  const int tid = threadIdx.x;
  const int c = tid & 63;                                     // column 0..63
  const int g = __builtin_amdgcn_readfirstlane(tid >> 6);     // wave id 0..3 (scalar)
  const int bid = blockIdx.x;                                 // m*256 + b
  const int m = bid >> 8;
  const int b = bid & 255;

  const float* Xb = X + (size_t)b * (DIN * QD);
  const float* Wm = W + (size_t)m * (DOUT * DIN);

  float a[32];
#pragma unroll
  for (int k = 0; k < 32; ++k) a[k] = 0.f;

  // ---------------- Phase 1: GEMM  a[k] = Y[g+4k][c] = sum_i W[m][g+4k][i]*X[b][i][c]
  for (int kc = 0; kc < DIN; kc += 32) {
    float xv[32];
#pragma unroll
    for (int k = 0; k < 32; ++k) xv[k] = Xb[(kc + k) * QD + c];  // coalesced
#pragma unroll
    for (int rr = 0; rr < 32; ++rr) {
      const float* Wr = Wm + (g + 4 * rr) * DIN + kc;  // wave-uniform address
      float acc = a[rr];
#pragma unroll
      for (int k4 = 0; k4 < 8; ++k4) {
        float4 w4 = *(const float4*)(Wr + k4 * 4);
        acc = fmaf(w4.x, xv[k4 * 4 + 0], acc);
        acc = fmaf(w4.y, xv[k4 * 4 + 1], acc);
        acc = fmaf(w4.z, xv[k4 * 4 + 2], acc);
        acc = fmaf(w4.w, xv[k4 * 4 + 3], acc);
      }
      a[rr] = acc;
    }
  }

  // ---------------- prime step-0 norm/alpha
  if (c == 0) {
    float s = 0.f;
#pragma unroll
    for (int k = 0; k < 32; ++k) {
      int r = g + 4 * k;
      if (r > 0) s = fmaf(a[k], a[k], s);
    }
    Pred[g] = s;
    if (g == 0) Sc[1] = a[0];
  }
  __syncthreads();

  // ---------------- Phase 2a: sgeqr2 (LAPACK Householder, sign convention slarfg)
  for (int j = 0; j < QD; ++j) {
    if (tid == 0) {
      float xn2 = Pred[0] + Pred[1] + Pred[2] + Pred[3];
      float alpha = Sc[1];
      float tau, invs;
      if (xn2 == 0.f) { tau = 0.f; invs = 0.f; }
      else {
        float mag = sqrtf(alpha * alpha + xn2);
        float beta = (alpha >= 0.f) ? -mag : mag;
        tau = (beta - alpha) / beta;
        invs = 1.f / (alpha - beta);
      }
      Tau[j] = tau; Sc[0] = invs;
    }
    __syncthreads();
    float* V = Vbuf[j & 1];
    if (c == j) {                       // scale own column, publish v (v[j]=1)
      float invs = Sc[0];
#pragma unroll
      for (int k = 0; k < 32; ++k) {
        int r = g + 4 * k;
        if (r > j) { a[k] *= invs; V[r] = a[k]; }
        else if (r == j) V[r] = 1.f;
      }
    }
    __syncthreads();
    float tau = Tau[j];
    if (c > j) {                        // p = v^T A[j:,c]
      float p = 0.f;
#pragma unroll
      for (int k = 0; k < 32; ++k) {
        int r = g + 4 * k;
        if (r >= j) p = fmaf(V[r], a[k], p);
      }
      P[g][c] = p;
    }
    __syncthreads();
    if (g == 0 && c > j) Wk[c] = tau * (P[0][c] + P[1][c] + P[2][c] + P[3][c]);
    __syncthreads();
    if (c > j) {                        // A[j:,c] -= w_c * v
      float w = Wk[c];
#pragma unroll
      for (int k = 0; k < 32; ++k) {
        int r = g + 4 * k;
        if (r >= j) a[k] = fmaf(-w, V[r], a[k]);
      }
    }
    if (c == j + 1) {                   // fused: next column's norm^2 + alpha
      float s = 0.f;
#pragma unroll
      for (int k = 0; k < 32; ++k) {
        int r = g + 4 * k;
        if (r > j + 1) s = fmaf(a[k], a[k], s);
      }
      Pred[g] = s;
      if (g == ((j + 1) & 3)) Sc[1] = a[(j + 1) >> 2];
    }
    __syncthreads();
  }

  // ---------------- Phase 2b: sorg2r (build Q backward)
  for (int i = QD - 1; i >= 0; --i) {
    float* V = Vbuf[i & 1];
    if (c == i) {                       // publish v_i
#pragma unroll
      for (int k = 0; k < 32; ++k) {
        int r = g + 4 * k;
        if (r > i) V[r] = a[k];
        else if (r == i) V[r] = 1.f;
      }
    }
    __syncthreads();
    float tau = Tau[i];
    if (c > i) {
      float p = 0.f;
#pragma unroll
      for (int k = 0; k < 32; ++k) {
        int r = g + 4 * k;
        if (r >= i) p = fmaf(V[r], a[k], p);
      }
      P[g][c] = p;
    }
    __syncthreads();
    if (g == 0 && c > i) Wk[c] = tau * (P[0][c] + P[1][c] + P[2][c] + P[3][c]);
    __syncthreads();
    if (c > i) {
      float w = Wk[c];
#pragma unroll
      for (int k = 0; k < 32; ++k) {
        int r = g + 4 * k;
        if (r >= i) a[k] = fmaf(-w, V[r], a[k]);
      }
    } else if (c == i) {                // set column i: 0 / 1-tau / -tau*v
#pragma unroll
      for (int k = 0; k < 32; ++k) {
        int r = g + 4 * k;
        if (r < i) a[k] = 0.f;
        else if (r == i) a[k] = 1.f - tau;
        else a[k] = -tau * a[k];
      }
    }
    // no sync needed: next step writes the OTHER V buffer; readers of this
    // buffer are >=2 syncs behind by construction
  }

  // ---------------- Phase 3: store Q (coalesced: r uniform per wave, c=lane)
  float* O = out + (size_t)bid * (DOUT * QD);
#pragma unroll
  for (int k = 0; k < 32; ++k) {
    int r = g + 4 * k;
    O[r * QD + c] = a[k];
  }
}

extern "C" void kernel_launch(void* const* d_in, const int* in_sizes, int n_in,
                              void* d_out, int out_size, void* d_ws, size_t ws_size,
                              hipStream_t stream) {
  const float* X = (const float*)d_in[0];   // (256, 512, 64) fp32
  const float* W = (const float*)d_in[1];   // (16, 128, 512) fp32
  float* out = (float*)d_out;               // (4096, 128, 64) fp32
  frmap_qr<<<NMAPS * NB, 256, 0, stream>>>(X, W, out);
}

// Round 4
// 2119.787 us; speedup vs baseline: 1.9718x; 1.4798x over previous
//
#include <hip/hip_runtime.h>
#include <math.h>

#define NMAPS 16
#define DIN 512
#define DOUT 128
#define QD 64
#define NB 256

// One block (256 thr = 4 waves) per matrix. Thread (c,g) owns rows r=g+4k of
// column c in registers a[32].
// LESSON (R3): an exec-masked ds_write followed by a same-wave ds_read of the
// same LDS address does NOT reliably return the written data without a fence
// (deterministic corruption, absmax 1.34, arithmetic otherwise bitwise-equal
// to the passing R2). Publish->read is now fenced with __syncthreads().
__global__ __launch_bounds__(256, 4) void frmap_qr(const float* __restrict__ X,
                                                   const float* __restrict__ W,
                                                   float* __restrict__ out) {
  __shared__ __align__(16) float Vp[4][32];  // wave-g slice of v (rows g+4k)
  __shared__ float P[4][QD];                 // per-wave partial dots
  __shared__ float Pred[4];                  // norm^2 partials for next pivot
  __shared__ float Tau[QD];
  __shared__ float Alpha;                    // next pivot value

  const int tid = threadIdx.x;
  const int c = tid & 63;
  const int g = __builtin_amdgcn_readfirstlane(tid >> 6);
  const int bid = blockIdx.x;                // m*256 + b
  const int m = bid >> 8;
  const int b = bid & 255;

  const float* Xb = X + (size_t)b * (DIN * QD);
  const float* Wm = W + (size_t)m * (DOUT * DIN);

  float a[32];
#pragma unroll
  for (int k = 0; k < 32; ++k) a[k] = 0.f;

  // ---------------- Phase 1: GEMM (bit-identical to R2)
  for (int kc = 0; kc < DIN; kc += 32) {
    float xv[32];
#pragma unroll
    for (int k = 0; k < 32; ++k) xv[k] = Xb[(kc + k) * QD + c];  // coalesced
#pragma unroll
    for (int rr = 0; rr < 32; ++rr) {
      const float* Wr = Wm + (g + 4 * rr) * DIN + kc;  // wave-uniform -> s_load
      float acc = a[rr];
#pragma unroll
      for (int k4 = 0; k4 < 8; ++k4) {
        float4 w4 = *(const float4*)(Wr + k4 * 4);
        acc = fmaf(w4.x, xv[k4 * 4 + 0], acc);
        acc = fmaf(w4.y, xv[k4 * 4 + 1], acc);
        acc = fmaf(w4.z, xv[k4 * 4 + 2], acc);
        acc = fmaf(w4.w, xv[k4 * 4 + 3], acc);
      }
      a[rr] = acc;
    }
  }

  // prime step-0 norm/alpha
  if (c == 0) {
    float s = 0.f;
#pragma unroll
    for (int k = 0; k < 32; ++k) {
      int r = g + 4 * k;
      if (r > 0) s = fmaf(a[k], a[k], s);
    }
    Pred[g] = s;
    if (g == 0) Alpha = a[0];
  }
  __syncthreads();

  // ---------------- Phase 2a: sgeqr2 (3 barriers/step)
  for (int j = 0; j < QD; ++j) {
    // all threads compute tau/invs redundantly (IEEE-deterministic, same bits)
    float xn2 = Pred[0] + Pred[1] + Pred[2] + Pred[3];
    float alpha = Alpha;
    float tau, invs;
    if (xn2 == 0.f) { tau = 0.f; invs = 0.f; }
    else {
      float mag = sqrtf(alpha * alpha + xn2);
      float beta = (alpha >= 0.f) ? -mag : mag;   // slarfg sign convention
      tau = (beta - alpha) / beta;
      invs = 1.f / (alpha - beta);
    }
    if (tid == 0) Tau[j] = tau;

    if (c == j) {  // scale own column; publish v with explicit 0s / 1
#pragma unroll
      for (int k4 = 0; k4 < 8; ++k4) {
        float4 v4;
        float* vv = (float*)&v4;
#pragma unroll
        for (int e = 0; e < 4; ++e) {
          int k = k4 * 4 + e;
          int r = g + 4 * k;
          float nv;
          if (r > j) { a[k] *= invs; nv = a[k]; }
          else nv = (r == j) ? 1.f : 0.f;
          vv[e] = nv;
        }
        *(float4*)&Vp[g][k4 * 4] = v4;
      }
    }
    __syncthreads();                   // B1: publish visible (R3 lesson)

    float vr[32];
#pragma unroll
    for (int k4 = 0; k4 < 8; ++k4) {
      float4 v4 = *(const float4*)&Vp[g][k4 * 4];
      vr[k4 * 4 + 0] = v4.x; vr[k4 * 4 + 1] = v4.y;
      vr[k4 * 4 + 2] = v4.z; vr[k4 * 4 + 3] = v4.w;
    }
    if (c > j) {                       // unmasked dot (zeros in vr mask r<j)
      float p = 0.f;
#pragma unroll
      for (int k = 0; k < 32; ++k) p = fmaf(vr[k], a[k], p);
      P[g][c] = p;
    }
    __syncthreads();                   // B2: P partials visible
    if (c > j) {
      float w = tau * (P[0][c] + P[1][c] + P[2][c] + P[3][c]);
#pragma unroll
      for (int k = 0; k < 32; ++k) a[k] = fmaf(-w, vr[k], a[k]);
    }
    if (c == j + 1) {                  // fused next-column norm^2 + alpha
      float s = 0.f;
#pragma unroll
      for (int k = 0; k < 32; ++k) {
        int r = g + 4 * k;
        if (r > j + 1) s = fmaf(a[k], a[k], s);
        if (r == j + 1) Alpha = a[k];  // static reg index
      }
      Pred[g] = s;
    }
    __syncthreads();                   // B3: fences Pred/Alpha/P for next step
  }

  // ---------------- Phase 2b: sorg2r (2 barriers/step)
  for (int i = QD - 1; i >= 0; --i) {
    float tau = Tau[i];                // uniform broadcast read
    if (c == i) {                      // publish v_i
#pragma unroll
      for (int k4 = 0; k4 < 8; ++k4) {
        float4 v4;
        float* vv = (float*)&v4;
#pragma unroll
        for (int e = 0; e < 4; ++e) {
          int k = k4 * 4 + e;
          int r = g + 4 * k;
          vv[e] = (r > i) ? a[k] : ((r == i) ? 1.f : 0.f);
        }
        *(float4*)&Vp[g][k4 * 4] = v4;
      }
    }
    __syncthreads();                   // B1: publish visible; also fences the
                                       // previous step's P reads vs our P write
    float vr[32];
#pragma unroll
    for (int k4 = 0; k4 < 8; ++k4) {
      float4 v4 = *(const float4*)&Vp[g][k4 * 4];
      vr[k4 * 4 + 0] = v4.x; vr[k4 * 4 + 1] = v4.y;
      vr[k4 * 4 + 2] = v4.z; vr[k4 * 4 + 3] = v4.w;
    }
    if (c > i) {
      float p = 0.f;
#pragma unroll
      for (int k = 0; k < 32; ++k) p = fmaf(vr[k], a[k], p);
      P[g][c] = p;
    }
    __syncthreads();                   // B2: P partials visible
    if (c > i) {
      float w = tau * (P[0][c] + P[1][c] + P[2][c] + P[3][c]);
#pragma unroll
      for (int k = 0; k < 32; ++k) a[k] = fmaf(-w, vr[k], a[k]);
    } else if (c == i) {               // own column: 0 / 1-tau / -tau*v
#pragma unroll
      for (int k = 0; k < 32; ++k) {
        int r = g + 4 * k;
        float val = a[k];
        float nv;
        if (r == i) nv = 1.f - tau;
        else if (r < i) nv = 0.f;
        else nv = -tau * val;
        a[k] = nv;
      }
    }
    // no end barrier: next step's B1 fences P-write vs this step's P-read,
    // and Vp rewrite (next step, pre-B1) vs this step's vr reads is fenced
    // by this step's B2.
  }

  // ---------------- Phase 3: store Q (registers only)
  float* O = out + (size_t)bid * (DOUT * QD);
#pragma unroll
  for (int k = 0; k < 32; ++k) O[(g + 4 * k) * QD + c] = a[k];
}

extern "C" void kernel_launch(void* const* d_in, const int* in_sizes, int n_in,
                              void* d_out, int out_size, void* d_ws, size_t ws_size,
                              hipStream_t stream) {
  const float* X = (const float*)d_in[0];   // (256, 512, 64) fp32
  const float* W = (const float*)d_in[1];   // (16, 128, 512) fp32
  float* out = (float*)d_out;               // (4096, 128, 64) fp32
  frmap_qr<<<NMAPS * NB, 256, 0, stream>>>(X, W, out);
}

// Round 5
// 1945.033 us; speedup vs baseline: 2.1490x; 1.0898x over previous
//
#include <hip/hip_runtime.h>
#include <math.h>

#define NMAPS 16
#define DIN 512
#define DOUT 128
#define QD 64

// One block (256 thr) per matrix.
// GEMM mapping: (oc = tid&63, og = tid>>6) owns rows og+4k of column oc (wave-
//   uniform W rows -> scalar loads).
// QR mapping (after exact LDS transpose): (c = tid>>2, t = tid&3) owns rows
//   t+4k of column c; the 4 row-partials of a column sit in ONE quad of ONE
//   wave -> reductions are in-quad shuffles, no LDS, no barrier.
// 1 barrier per QR step (double-buffered V; publisher self-carries tau/invs in
// registers). All arithmetic bitwise-identical to the passing R4 kernel.
__global__ __launch_bounds__(256, 4) void frmap_qr(const float* __restrict__ X,
                                                   const float* __restrict__ W,
                                                   float* __restrict__ out) {
  __shared__ __align__(16) float Vq[2][4][32];  // [buf][t][k] = v_{t+4k}
  __shared__ float Tau[QD];
  __shared__ __align__(16) float Buf[64][65];   // transpose staging (64-row chunks)

  const int tid = threadIdx.x;
  const int oc = tid & 63;                                  // GEMM column
  const int og = __builtin_amdgcn_readfirstlane(tid >> 6);  // GEMM row class
  const int c = tid >> 2;                                   // QR column
  const int t = tid & 3;                                    // QR row class
  const int lb = tid & 60;                                  // quad base lane

  const int bid = blockIdx.x;  // m*256 + b
  const int m = bid >> 8;
  const int b = bid & 255;
  const float* Xb = X + (size_t)b * (DIN * QD);
  const float* Wm = W + (size_t)m * (DOUT * DIN);

  float a[32];
#pragma unroll
  for (int k = 0; k < 32; ++k) a[k] = 0.f;

  // ---------------- Phase 1: GEMM (bit-identical to R4)
  for (int kc = 0; kc < DIN; kc += 32) {
    float xv[32];
#pragma unroll
    for (int k = 0; k < 32; ++k) xv[k] = Xb[(kc + k) * QD + oc];  // coalesced
#pragma unroll
    for (int rr = 0; rr < 32; ++rr) {
      const float* Wr = Wm + (og + 4 * rr) * DIN + kc;  // wave-uniform
      float acc = a[rr];
#pragma unroll
      for (int k4 = 0; k4 < 8; ++k4) {
        float4 w4 = *(const float4*)(Wr + k4 * 4);
        acc = fmaf(w4.x, xv[k4 * 4 + 0], acc);
        acc = fmaf(w4.y, xv[k4 * 4 + 1], acc);
        acc = fmaf(w4.z, xv[k4 * 4 + 2], acc);
        acc = fmaf(w4.w, xv[k4 * 4 + 3], acc);
      }
      a[rr] = acc;
    }
  }

  // ---------------- Phase 1.5: exact ownership transpose (pure data movement)
#pragma unroll
  for (int q = 0; q < 2; ++q) {  // chunk q = rows [64q, 64q+64)
    if (q) __syncthreads();      // fence Buf reuse
#pragma unroll
    for (int kk = 0; kk < 16; ++kk) Buf[og + 4 * kk][oc] = a[16 * q + kk];
    __syncthreads();
#pragma unroll
    for (int kk = 0; kk < 16; ++kk) a[16 * q + kk] = Buf[t + 4 * kk][c];
  }

  // ---------------- prime step-0: quad c==0 computes tau/invs (same bits as R4)
  float tau_mine = 0.f, invs_mine = 0.f;
  if (c == 0) {
    float s = 0.f, myalpha = 0.f;
#pragma unroll
    for (int k = 0; k < 32; ++k) {
      int r = t + 4 * k;
      if (r > 0) s = fmaf(a[k], a[k], s);
      if (r == 0) myalpha = a[k];
    }
    float s0 = __shfl(s, lb + 0), s1 = __shfl(s, lb + 1);
    float s2 = __shfl(s, lb + 2), s3 = __shfl(s, lb + 3);
    float xn2 = ((s0 + s1) + s2) + s3;               // == Pred0+Pred1+Pred2+Pred3
    float alpha = __shfl(myalpha, lb + 0);
    float tau, invs;
    if (xn2 == 0.f) { tau = 0.f; invs = 0.f; }
    else {
      float mag = sqrtf(alpha * alpha + xn2);
      float beta = (alpha >= 0.f) ? -mag : mag;      // slarfg sign convention
      tau = (beta - alpha) / beta;
      invs = 1.f / (alpha - beta);
    }
    tau_mine = tau; invs_mine = invs;
    if (t == 0) Tau[0] = tau;                        // fenced by B(0) below
  }

  // ---------------- Phase 2a: sgeqr2, 1 barrier/step
  for (int j = 0; j < QD; ++j) {
    if (c == j) {  // scale own column with self-carried invs; publish v
      float* Vrow = &Vq[j & 1][t][0];
#pragma unroll
      for (int k4 = 0; k4 < 8; ++k4) {
        float4 v4;
        float* vv = (float*)&v4;
#pragma unroll
        for (int e = 0; e < 4; ++e) {
          int k = 4 * k4 + e;
          int r = t + 4 * k;
          float nv;
          if (r > j) { a[k] *= invs_mine; nv = a[k]; }
          else nv = (r == j) ? 1.f : 0.f;
          vv[e] = nv;
        }
        *(float4*)&Vrow[4 * k4] = v4;
      }
    }
    __syncthreads();  // publish visible; fences Tau[j]; fences Vq[j&1] reuse
    if (c > j) {      // whole-wave execz skip once all 16 columns retired
      float taul = Tau[j];
      float vr[32];
#pragma unroll
      for (int k4 = 0; k4 < 8; ++k4) {
        float4 v4 = *(const float4*)&Vq[j & 1][t][4 * k4];
        vr[4 * k4 + 0] = v4.x; vr[4 * k4 + 1] = v4.y;
        vr[4 * k4 + 2] = v4.z; vr[4 * k4 + 3] = v4.w;
      }
      float p = 0.f;
#pragma unroll
      for (int k = 0; k < 32; ++k) p = fmaf(vr[k], a[k], p);
      float q0 = __shfl(p, lb + 0), q1 = __shfl(p, lb + 1);
      float q2 = __shfl(p, lb + 2), q3 = __shfl(p, lb + 3);
      float w = taul * (((q0 + q1) + q2) + q3);      // == tau*(P0+P1+P2+P3)
#pragma unroll
      for (int k = 0; k < 32; ++k) a[k] = fmaf(-w, vr[k], a[k]);
      if (c == j + 1) {  // fused: next pivot norm + tau/invs (this quad only)
        float s = 0.f, myalpha = 0.f;
#pragma unroll
        for (int k = 0; k < 32; ++k) {
          int r = t + 4 * k;
          if (r > j + 1) s = fmaf(a[k], a[k], s);
          if (r == j + 1) myalpha = a[k];            // static reg index
        }
        float s0 = __shfl(s, lb + 0), s1 = __shfl(s, lb + 1);
        float s2 = __shfl(s, lb + 2), s3 = __shfl(s, lb + 3);
        float xn2 = ((s0 + s1) + s2) + s3;
        float alpha = __shfl(myalpha, lb + ((j + 1) & 3));
        float tau, invs;
        if (xn2 == 0.f) { tau = 0.f; invs = 0.f; }
        else {
          float mag = sqrtf(alpha * alpha + xn2);
          float beta = (alpha >= 0.f) ? -mag : mag;
          tau = (beta - alpha) / beta;
          invs = 1.f / (alpha - beta);
        }
        tau_mine = tau; invs_mine = invs;
        if (t == 0) Tau[j + 1] = tau;                // read after B(j+1): fenced
      }
    }
  }

  __syncthreads();  // phase boundary: protect Vq[1] (j=63 readers vs i=63 publish)

  // ---------------- Phase 2b: sorg2r, 1 barrier/step
  for (int i = QD - 1; i >= 0; --i) {
    if (c == i) {  // publish v_i (raw a, explicit 1/0)
#pragma unroll
      for (int k4 = 0; k4 < 8; ++k4) {
        float4 v4;
        float* vv = (float*)&v4;
#pragma unroll
        for (int e = 0; e < 4; ++e) {
          int k = 4 * k4 + e;
          int r = t + 4 * k;
          vv[e] = (r > i) ? a[k] : ((r == i) ? 1.f : 0.f);
        }
        *(float4*)&Vq[i & 1][t][4 * k4] = v4;
      }
    }
    __syncthreads();  // publish visible; fences Vq[i&1] reuse via prior barriers
    if (c > i) {
      float taul = Tau[i];
      float vr[32];
#pragma unroll
      for (int k4 = 0; k4 < 8; ++k4) {
        float4 v4 = *(const float4*)&Vq[i & 1][t][4 * k4];
        vr[4 * k4 + 0] = v4.x; vr[4 * k4 + 1] = v4.y;
        vr[4 * k4 + 2] = v4.z; vr[4 * k4 + 3] = v4.w;
      }
      float p = 0.f;
#pragma unroll
      for (int k = 0; k < 32; ++k) p = fmaf(vr[k], a[k], p);
      float q0 = __shfl(p, lb + 0), q1 = __shfl(p, lb + 1);
      float q2 = __shfl(p, lb + 2), q3 = __shfl(p, lb + 3);
      float w = taul * (((q0 + q1) + q2) + q3);
#pragma unroll
      for (int k = 0; k < 32; ++k) a[k] = fmaf(-w, vr[k], a[k]);
    } else if (c == i) {  // own column: 0 / 1-tau / -tau*v
      float taul = Tau[i];
#pragma unroll
      for (int k = 0; k < 32; ++k) {
        int r = t + 4 * k;
        float val = a[k];
        float nv;
        if (r == i) nv = 1.f - taul;
        else if (r < i) nv = 0.f;
        else nv = -taul * val;
        a[k] = nv;
      }
    }
  }

  // ---------------- Phase 3: store Q (4x64B segments per instr)
  float* O = out + (size_t)bid * (DOUT * QD);
#pragma unroll
  for (int k = 0; k < 32; ++k) O[(t + 4 * k) * QD + c] = a[k];
}

extern "C" void kernel_launch(void* const* d_in, const int* in_sizes, int n_in,
                              void* d_out, int out_size, void* d_ws, size_t ws_size,
                              hipStream_t stream) {
  const float* X = (const float*)d_in[0];   // (256, 512, 64) fp32
  const float* W = (const float*)d_in[1];   // (16, 128, 512) fp32
  float* out = (float*)d_out;               // (4096, 128, 64) fp32
  frmap_qr<<<NMAPS * 256, 256, 0, stream>>>(X, W, out);
}

// Round 6
// 1926.625 us; speedup vs baseline: 2.1695x; 1.0096x over previous
//
#include <hip/hip_runtime.h>
#include <math.h>

#define NMAPS 16
#define DIN 512
#define DOUT 128
#define QD 64

// DPP quad broadcast: result = value of lane (quadbase + Q) for compile-time Q.
// Bitwise-identical to __shfl(x, lb+Q) but stays on the VALU pipe (no
// ds_bpermute / LDS traffic on the per-step critical path).
template <int CTRL>
__device__ __forceinline__ float qbc(float x) {
  return __int_as_float(__builtin_amdgcn_update_dpp(
      0, __float_as_int(x), CTRL, 0xF, 0xF, true));
}
// ((s0+s1)+s2)+s3 -- same order as the R4/R5 P[0]+P[1]+P[2]+P[3] reduction.
__device__ __forceinline__ float quadSum4(float x) {
  float s0 = qbc<0x00>(x), s1 = qbc<0x55>(x);
  float s2 = qbc<0xAA>(x), s3 = qbc<0xFF>(x);
  return ((s0 + s1) + s2) + s3;
}

// slarfg sign convention (LAPACK): identical formula/bits as R4/R5.
__device__ __forceinline__ void make_tau(float xn2, float alpha, float& tau,
                                         float& invs) {
  if (xn2 == 0.f) { tau = 0.f; invs = 0.f; }
  else {
    float mag = sqrtf(alpha * alpha + xn2);
    float beta = (alpha >= 0.f) ? -mag : mag;
    tau = (beta - alpha) / beta;
    invs = 1.f / (alpha - beta);
  }
}

// Publish column `piv`'s Householder vector (explicit 0s below-diag=above rows,
// 1 at pivot). SCALE=true also applies a[k] *= invs for r > piv (sgeqr2 path).
template <bool SCALE>
__device__ __forceinline__ void publish_col(float (&a)[32], const int t,
                                            const int piv, const float invs,
                                            float* __restrict__ Vrow) {
#pragma unroll
  for (int k4 = 0; k4 < 8; ++k4) {
    float4 v4;
    float* vv = (float*)&v4;
#pragma unroll
    for (int e = 0; e < 4; ++e) {
      int k = 4 * k4 + e;
      int r = t + 4 * k;
      float nv;
      if (r > piv) {
        if (SCALE) a[k] *= invs;
        nv = a[k];
      } else nv = (r == piv) ? 1.f : 0.f;
      vv[e] = nv;
    }
    *(float4*)&Vrow[4 * k4] = v4;
  }
}

__device__ __forceinline__ void load_v(float (&vr)[32],
                                       const float* __restrict__ Vrow) {
#pragma unroll
  for (int k4 = 0; k4 < 8; ++k4) {
    float4 v4 = *(const float4*)&Vrow[4 * k4];
    vr[4 * k4 + 0] = v4.x; vr[4 * k4 + 1] = v4.y;
    vr[4 * k4 + 2] = v4.z; vr[4 * k4 + 3] = v4.w;
  }
}

// One block (256 thr) per matrix.
// GEMM mapping: (oc = tid&63, og = tid>>6) owns rows og+4k (wave-uniform W).
// QR mapping (after LDS transpose): (c = tid>>2, t = tid&3) owns rows t+4k of
// column c; a column's 4 partials live in one 4-lane quad -> DPP reduce.
// V rows padded to 36 floats: word offset t*36+4k4 -> banks 4t+4k4.. disjoint
// across t -> conflict-free b128 publish/read (R5's [4][32] was 4-way).
// Publish-ahead: column j+1's tau/scale/publish runs at the TAIL of step j
// (double-buffered V), so the post-barrier path is load->dot->reduce->update.
__global__ __launch_bounds__(256, 4) void frmap_qr(const float* __restrict__ X,
                                                   const float* __restrict__ W,
                                                   float* __restrict__ out) {
  __shared__ __align__(16) float Vq[2][4][36];
  __shared__ float Tau[QD];
  __shared__ __align__(16) float Buf[64][65];  // transpose staging

  const int tid = threadIdx.x;
  const int oc = tid & 63;
  const int og = __builtin_amdgcn_readfirstlane(tid >> 6);
  const int c = tid >> 2;
  const int t = tid & 3;

  const int bid = blockIdx.x;  // m*256 + b
  const int m = bid >> 8;
  const int b = bid & 255;
  const float* Xb = X + (size_t)b * (DIN * QD);
  const float* Wm = W + (size_t)m * (DOUT * DIN);

  float a[32];
#pragma unroll
  for (int k = 0; k < 32; ++k) a[k] = 0.f;

  // ---------------- Phase 1: GEMM (bit-identical to R4/R5)
  for (int kc = 0; kc < DIN; kc += 32) {
    float xv[32];
#pragma unroll
    for (int k = 0; k < 32; ++k) xv[k] = Xb[(kc + k) * QD + oc];  // coalesced
#pragma unroll
    for (int rr = 0; rr < 32; ++rr) {
      const float* Wr = Wm + (og + 4 * rr) * DIN + kc;  // wave-uniform
      float acc = a[rr];
#pragma unroll
      for (int k4 = 0; k4 < 8; ++k4) {
        float4 w4 = *(const float4*)(Wr + k4 * 4);
        acc = fmaf(w4.x, xv[k4 * 4 + 0], acc);
        acc = fmaf(w4.y, xv[k4 * 4 + 1], acc);
        acc = fmaf(w4.z, xv[k4 * 4 + 2], acc);
        acc = fmaf(w4.w, xv[k4 * 4 + 3], acc);
      }
      a[rr] = acc;
    }
  }

  // ---------------- Phase 1.5: exact ownership transpose
#pragma unroll
  for (int q = 0; q < 2; ++q) {
    if (q) __syncthreads();
#pragma unroll
    for (int kk = 0; kk < 16; ++kk) Buf[og + 4 * kk][oc] = a[16 * q + kk];
    __syncthreads();
#pragma unroll
    for (int kk = 0; kk < 16; ++kk) a[16 * q + kk] = Buf[t + 4 * kk][c];
  }

  // ---------------- prologue: quad 0 makes tau0/invs0, scales, publishes V_0
  if (c == 0) {
    float s = 0.f, myalpha = 0.f;
#pragma unroll
    for (int k = 0; k < 32; ++k) {
      int r = t + 4 * k;
      if (r > 0) s = fmaf(a[k], a[k], s);
      if (r == 0) myalpha = a[k];
    }
    float xn2 = quadSum4(s);
    float alpha = qbc<0x00>(myalpha);
    float tau, invs;
    make_tau(xn2, alpha, tau, invs);
    if (t == 0) Tau[0] = tau;
    publish_col<true>(a, t, 0, invs, &Vq[0][t][0]);
  }
  __syncthreads();  // B0: V_0 / Tau[0] visible

  // ---------------- Phase 2a: sgeqr2 (1 barrier/step, publish-ahead)
  for (int j = 0; j < QD - 1; ++j) {   // step 63 would be empty
    if (c > j) {
      float taul = Tau[j];
      float vr[32];
      load_v(vr, &Vq[j & 1][t][0]);
      float p = 0.f;
#pragma unroll
      for (int k = 0; k < 32; ++k) p = fmaf(vr[k], a[k], p);
      float w = taul * quadSum4(p);
#pragma unroll
      for (int k = 0; k < 32; ++k) a[k] = fmaf(-w, vr[k], a[k]);
      if (c == j + 1) {  // tail: next pivot's tau/scale/publish (hidden here)
        float s = 0.f, myalpha = 0.f;
#pragma unroll
        for (int k = 0; k < 32; ++k) {
          int r = t + 4 * k;
          if (r > j + 1) s = fmaf(a[k], a[k], s);
          if (r == j + 1) myalpha = a[k];  // static reg index
        }
        float xn2 = quadSum4(s);
        float alpha;
        switch ((j + 1) & 3) {  // j wave-uniform -> scalar branch
          case 0:  alpha = qbc<0x00>(myalpha); break;
          case 1:  alpha = qbc<0x55>(myalpha); break;
          case 2:  alpha = qbc<0xAA>(myalpha); break;
          default: alpha = qbc<0xFF>(myalpha); break;
        }
        float tau, invs;
        make_tau(xn2, alpha, tau, invs);
        if (t == 0) Tau[j + 1] = tau;
        publish_col<true>(a, t, j + 1, invs, &Vq[(j + 1) & 1][t][0]);
      }
    }
    __syncthreads();  // end of step j (fences V_{j+1}, Tau[j+1], buffer reuse)
  }
  // after j=62's barrier: V_63 (scaled) sits in Vq[1], all taus written.

  // ---------------- Phase 2b: sorg2r (1 barrier/step, publish-ahead)
  for (int i = QD - 1; i >= 0; --i) {
    if (c > i) {
      float taul = Tau[i];
      float vr[32];
      load_v(vr, &Vq[i & 1][t][0]);
      float p = 0.f;
#pragma unroll
      for (int k = 0; k < 32; ++k) p = fmaf(vr[k], a[k], p);
      float w = taul * quadSum4(p);
#pragma unroll
      for (int k = 0; k < 32; ++k) a[k] = fmaf(-w, vr[k], a[k]);
    } else if (c == i) {  // own column: 0 / 1-tau / -tau*v
      float taul = Tau[i];
#pragma unroll
      for (int k = 0; k < 32; ++k) {
        int r = t + 4 * k;
        float val = a[k];
        float nv;
        if (r == i) nv = 1.f - taul;
        else if (r < i) nv = 0.f;
        else nv = -taul * val;
        a[k] = nv;
      }
    } else if (c == i - 1) {  // idle quad publishes V_{i-1} for next step
      publish_col<false>(a, t, i - 1, 0.f, &Vq[(i - 1) & 1][t][0]);
    }
    if (i) __syncthreads();  // no LDS use after i=0
  }

  // ---------------- Phase 3: store Q
  float* O = out + (size_t)bid * (DOUT * QD);
#pragma unroll
  for (int k = 0; k < 32; ++k) O[(t + 4 * k) * QD + c] = a[k];
}

extern "C" void kernel_launch(void* const* d_in, const int* in_sizes, int n_in,
                              void* d_out, int out_size, void* d_ws, size_t ws_size,
                              hipStream_t stream) {
  const float* X = (const float*)d_in[0];   // (256, 512, 64) fp32
  const float* W = (const float*)d_in[1];   // (16, 128, 512) fp32
  float* out = (float*)d_out;               // (4096, 128, 64) fp32
  frmap_qr<<<NMAPS * 256, 256, 0, stream>>>(X, W, out);
}

// Round 7
// 586.368 us; speedup vs baseline: 7.1285x; 3.2857x over previous
//
#include <hip/hip_runtime.h>
#include <math.h>

#define NMAPS 16
#define DIN 512
#define DOUT 128
#define QD 64

typedef __attribute__((ext_vector_type(8))) short bf16x8;  // 8 bf16 (4 VGPR)
typedef __attribute__((ext_vector_type(4))) float f32x4;

#define WS 40  // LDS row stride (ushorts) for W tiles: 80B -> b128-aligned rows
#define XS 40  // LDS col stride (ushorts) for XT tiles

// bf16 split helpers (RNE). x = bf2f(hi) + bf2f(lo) + O(2^-18 |x|).
__device__ __forceinline__ unsigned short f2bf(float x) {
  unsigned int u = __float_as_uint(x);
  return (unsigned short)((u + 0x7FFFu + ((u >> 16) & 1u)) >> 16);
}
__device__ __forceinline__ float bf2f(unsigned short h) {
  return __uint_as_float(((unsigned int)h) << 16);
}

// DPP quad broadcast (lane quadbase+Q), VALU-pipe; bitwise == __shfl(x, lb+Q).
template <int CTRL>
__device__ __forceinline__ float qbc(float x) {
  return __int_as_float(__builtin_amdgcn_update_dpp(
      0, __float_as_int(x), CTRL, 0xF, 0xF, true));
}
__device__ __forceinline__ float quadSum4(float x) {
  float s0 = qbc<0x00>(x), s1 = qbc<0x55>(x);
  float s2 = qbc<0xAA>(x), s3 = qbc<0xFF>(x);
  return ((s0 + s1) + s2) + s3;
}

// slarfg sign convention (LAPACK) — unchanged from R4-R6.
__device__ __forceinline__ void make_tau(float xn2, float alpha, float& tau,
                                         float& invs) {
  if (xn2 == 0.f) { tau = 0.f; invs = 0.f; }
  else {
    float mag = sqrtf(alpha * alpha + xn2);
    float beta = (alpha >= 0.f) ? -mag : mag;
    tau = (beta - alpha) / beta;
    invs = 1.f / (alpha - beta);
  }
}

template <bool SCALE>
__device__ __forceinline__ void publish_col(float (&a)[32], const int t,
                                            const int piv, const float invs,
                                            float* __restrict__ Vrow) {
#pragma unroll
  for (int k4 = 0; k4 < 8; ++k4) {
    float4 v4;
    float* vv = (float*)&v4;
#pragma unroll
    for (int e = 0; e < 4; ++e) {
      int k = 4 * k4 + e;
      int r = t + 4 * k;
      float nv;
      if (r > piv) {
        if (SCALE) a[k] *= invs;
        nv = a[k];
      } else nv = (r == piv) ? 1.f : 0.f;
      vv[e] = nv;
    }
    *(float4*)&Vrow[4 * k4] = v4;
  }
}

__device__ __forceinline__ void load_v(float (&vr)[32],
                                       const float* __restrict__ Vrow) {
#pragma unroll
  for (int k4 = 0; k4 < 8; ++k4) {
    float4 v4 = *(const float4*)&Vrow[4 * k4];
    vr[4 * k4 + 0] = v4.x; vr[4 * k4 + 1] = v4.y;
    vr[4 * k4 + 2] = v4.z; vr[4 * k4 + 3] = v4.w;
  }
}

// GEMM staging (per K=32 chunk) unioned with the QR handoff buffer.
union SmemU {
  struct {
    unsigned short Wh[DOUT][WS];  // 128x40x2B = 10240
    unsigned short Wl[DOUT][WS];  // 10240
    unsigned short Xh[QD][XS];    // XT (col-major): 64x40x2B = 5120
    unsigned short Xl[QD][XS];    // 5120   -> total 30720 B
  } g;
  float Buf[64][65];              // 16640 B (Y handoff, 64-row chunks)
};

// One block (256 thr = 4 waves) per matrix (m,b).
// GEMM: Y = W@X via split-bf16 3-product MFMA (WhXh + WhXl + WlXh), K=32
//   chunks staged hi/lo in LDS; wave w owns rows [32w,32w+32) = 2x4 tiles of
//   16x16, acc in f32x4[2][4].
// QR: identical to R6 (1 barrier/step, DPP quad reduce, publish-ahead).
__global__ __launch_bounds__(256, 4) void frmap_qr(const float* __restrict__ X,
                                                   const float* __restrict__ W,
                                                   float* __restrict__ out) {
  __shared__ __align__(16) SmemU U;
  __shared__ __align__(16) float Vq[2][4][36];
  __shared__ float Tau[QD];

  const int tid = threadIdx.x;
  const int l = tid & 63;                                   // lane
  const int w = __builtin_amdgcn_readfirstlane(tid >> 6);   // wave 0..3
  const int c = tid >> 2;                                   // QR column
  const int t = tid & 3;                                    // QR row class

  const int bid = blockIdx.x;  // m*256 + b
  const int m = bid >> 8;
  const int b = bid & 255;
  const float* Xb = X + (size_t)b * (DIN * QD);
  const float* Wm = W + (size_t)m * (DOUT * DIN);

  // ---------------- Phase 1: MFMA GEMM over 16 K-chunks
  f32x4 acc[2][4];
#pragma unroll
  for (int tr = 0; tr < 2; ++tr)
#pragma unroll
    for (int tc = 0; tc < 4; ++tc)
      acc[tr][tc] = (f32x4){0.f, 0.f, 0.f, 0.f};

  const int fr = l & 15;   // row/col within 16x16 tile
  const int fg = l >> 4;   // k-group (8 bf16 each)

  for (int kc = 0; kc < DIN; kc += 32) {
    // -- load W chunk (128x32): thread handles float4 f = 4*tid+i (coalesced)
    ushort4 wh[4], wl[4];
    int wrow[4], wkw[4];
#pragma unroll
    for (int i = 0; i < 4; ++i) {
      int f = 4 * tid + i;
      wrow[i] = f >> 3;
      wkw[i] = f & 7;
      float4 v = *(const float4*)(Wm + wrow[i] * DIN + kc + 4 * wkw[i]);
      float p[4] = {v.x, v.y, v.z, v.w};
      unsigned short* hp = (unsigned short*)&wh[i];
      unsigned short* lp = (unsigned short*)&wl[i];
#pragma unroll
      for (int e = 0; e < 4; ++e) {
        unsigned short hh = f2bf(p[e]);
        hp[e] = hh;
        lp[e] = f2bf(p[e] - bf2f(hh));
      }
    }
    // -- load X chunk (32x64): col = l, k = kc + w + 4j (coalesced rows)
    unsigned short xh[8], xl[8];
#pragma unroll
    for (int j = 0; j < 8; ++j) {
      float xvj = Xb[(kc + w + 4 * j) * QD + l];
      unsigned short hh = f2bf(xvj);
      xh[j] = hh;
      xl[j] = f2bf(xvj - bf2f(hh));
    }

    __syncthreads();  // previous chunk's frag reads complete
#pragma unroll
    for (int i = 0; i < 4; ++i) {
      *(ushort4*)&U.g.Wh[wrow[i]][4 * wkw[i]] = wh[i];
      *(ushort4*)&U.g.Wl[wrow[i]][4 * wkw[i]] = wl[i];
    }
#pragma unroll
    for (int j = 0; j < 8; ++j) {        // XT: [col][k]
      U.g.Xh[l][w + 4 * j] = xh[j];
      U.g.Xl[l][w + 4 * j] = xl[j];
    }
    __syncthreads();  // chunk staged

    // -- 8 tiles x 3 products
#pragma unroll
    for (int tr = 0; tr < 2; ++tr) {
      bf16x8 ah = *(const bf16x8*)&U.g.Wh[32 * w + 16 * tr + fr][8 * fg];
      bf16x8 al = *(const bf16x8*)&U.g.Wl[32 * w + 16 * tr + fr][8 * fg];
#pragma unroll
      for (int tc = 0; tc < 4; ++tc) {
        bf16x8 bh = *(const bf16x8*)&U.g.Xh[16 * tc + fr][8 * fg];
        bf16x8 bl = *(const bf16x8*)&U.g.Xl[16 * tc + fr][8 * fg];
        acc[tr][tc] =
            __builtin_amdgcn_mfma_f32_16x16x32_bf16(ah, bh, acc[tr][tc], 0, 0, 0);
        acc[tr][tc] =
            __builtin_amdgcn_mfma_f32_16x16x32_bf16(ah, bl, acc[tr][tc], 0, 0, 0);
        acc[tr][tc] =
            __builtin_amdgcn_mfma_f32_16x16x32_bf16(al, bh, acc[tr][tc], 0, 0, 0);
      }
    }
  }

  // ---------------- Phase 1.5: acc -> Buf -> QR ownership (c=tid>>2, t=tid&3)
  // C/D layout (m89-verified): col = lane&15, row = (lane>>4)*4 + reg.
  float a[32];
  __syncthreads();  // all frag reads done before Buf (union) overwrite
  if (w < 2) {      // rows 0..63
#pragma unroll
    for (int tr = 0; tr < 2; ++tr)
#pragma unroll
      for (int tc = 0; tc < 4; ++tc)
#pragma unroll
        for (int v = 0; v < 4; ++v)
          U.Buf[32 * w + 16 * tr + 4 * fg + v][16 * tc + fr] = acc[tr][tc][v];
  }
  __syncthreads();
#pragma unroll
  for (int k = 0; k < 16; ++k) a[k] = U.Buf[t + 4 * k][c];
  __syncthreads();
  if (w >= 2) {     // rows 64..127
#pragma unroll
    for (int tr = 0; tr < 2; ++tr)
#pragma unroll
      for (int tc = 0; tc < 4; ++tc)
#pragma unroll
        for (int v = 0; v < 4; ++v)
          U.Buf[32 * (w - 2) + 16 * tr + 4 * fg + v][16 * tc + fr] =
              acc[tr][tc][v];
  }
  __syncthreads();
#pragma unroll
  for (int k = 16; k < 32; ++k) a[k] = U.Buf[t + 4 * k - 64][c];

  // ---------------- prologue: quad 0 makes tau0/invs0, scales, publishes V_0
  if (c == 0) {
    float s = 0.f, myalpha = 0.f;
#pragma unroll
    for (int k = 0; k < 32; ++k) {
      int r = t + 4 * k;
      if (r > 0) s = fmaf(a[k], a[k], s);
      if (r == 0) myalpha = a[k];
    }
    float xn2 = quadSum4(s);
    float alpha = qbc<0x00>(myalpha);
    float tau, invs;
    make_tau(xn2, alpha, tau, invs);
    if (t == 0) Tau[0] = tau;
    publish_col<true>(a, t, 0, invs, &Vq[0][t][0]);
  }
  __syncthreads();  // B0: V_0 / Tau[0] visible

  // ---------------- Phase 2a: sgeqr2 (1 barrier/step, publish-ahead) — R6
  for (int j = 0; j < QD - 1; ++j) {
    if (c > j) {
      float taul = Tau[j];
      float vr[32];
      load_v(vr, &Vq[j & 1][t][0]);
      float p = 0.f;
#pragma unroll
      for (int k = 0; k < 32; ++k) p = fmaf(vr[k], a[k], p);
      float wv = taul * quadSum4(p);
#pragma unroll
      for (int k = 0; k < 32; ++k) a[k] = fmaf(-wv, vr[k], a[k]);
      if (c == j + 1) {
        float s = 0.f, myalpha = 0.f;
#pragma unroll
        for (int k = 0; k < 32; ++k) {
          int r = t + 4 * k;
          if (r > j + 1) s = fmaf(a[k], a[k], s);
          if (r == j + 1) myalpha = a[k];  // static reg index
        }
        float xn2 = quadSum4(s);
        float alpha;
        switch ((j + 1) & 3) {
          case 0:  alpha = qbc<0x00>(myalpha); break;
          case 1:  alpha = qbc<0x55>(myalpha); break;
          case 2:  alpha = qbc<0xAA>(myalpha); break;
          default: alpha = qbc<0xFF>(myalpha); break;
        }
        float tau, invs;
        make_tau(xn2, alpha, tau, invs);
        if (t == 0) Tau[j + 1] = tau;
        publish_col<true>(a, t, j + 1, invs, &Vq[(j + 1) & 1][t][0]);
      }
    }
    __syncthreads();
  }

  __syncthreads();  // phase boundary (protect Vq[1])

  // ---------------- Phase 2b: sorg2r (1 barrier/step, publish-ahead) — R6
  for (int i = QD - 1; i >= 0; --i) {
    if (c > i) {
      float taul = Tau[i];
      float vr[32];
      load_v(vr, &Vq[i & 1][t][0]);
      float p = 0.f;
#pragma unroll
      for (int k = 0; k < 32; ++k) p = fmaf(vr[k], a[k], p);
      float wv = taul * quadSum4(p);
#pragma unroll
      for (int k = 0; k < 32; ++k) a[k] = fmaf(-wv, vr[k], a[k]);
    } else if (c == i) {
      float taul = Tau[i];
#pragma unroll
      for (int k = 0; k < 32; ++k) {
        int r = t + 4 * k;
        float val = a[k];
        float nv;
        if (r == i) nv = 1.f - taul;
        else if (r < i) nv = 0.f;
        else nv = -taul * val;
        a[k] = nv;
      }
    } else if (c == i - 1) {
      publish_col<false>(a, t, i - 1, 0.f, &Vq[(i - 1) & 1][t][0]);
    }
    if (i) __syncthreads();
  }

  // ---------------- Phase 3: store Q
  float* O = out + (size_t)bid * (DOUT * QD);
#pragma unroll
  for (int k = 0; k < 32; ++k) O[(t + 4 * k) * QD + c] = a[k];
}

extern "C" void kernel_launch(void* const* d_in, const int* in_sizes, int n_in,
                              void* d_out, int out_size, void* d_ws, size_t ws_size,
                              hipStream_t stream) {
  const float* X = (const float*)d_in[0];   // (256, 512, 64) fp32
  const float* W = (const float*)d_in[1];   // (16, 128, 512) fp32
  float* out = (float*)d_out;               // (4096, 128, 64) fp32
  frmap_qr<<<NMAPS * 256, 256, 0, stream>>>(X, W, out);
}

// Round 8
// 563.704 us; speedup vs baseline: 7.4150x; 1.0402x over previous
//
#include <hip/hip_runtime.h>
#include <math.h>

#define NMAPS 16
#define DIN 512
#define DOUT 128
#define QD 64

typedef __attribute__((ext_vector_type(8))) short bf16x8;  // 8 bf16 (4 VGPR)
typedef __attribute__((ext_vector_type(4))) float f32x4;

// bf16 split helpers (RNE). x = bf2f(hi) + bf2f(lo) + O(2^-18 |x|).
__device__ __forceinline__ unsigned short f2bf(float x) {
  unsigned int u = __float_as_uint(x);
  return (unsigned short)((u + 0x7FFFu + ((u >> 16) & 1u)) >> 16);
}
__device__ __forceinline__ float bf2f(unsigned short h) {
  return __uint_as_float(((unsigned int)h) << 16);
}

__device__ __forceinline__ void gload_lds16(const void* g, void* lds) {
  __builtin_amdgcn_global_load_lds(
      (const __attribute__((address_space(1))) unsigned int*)g,
      (__attribute__((address_space(3))) unsigned int*)lds, 16, 0, 0);
}

// DPP quad broadcast (lane quadbase+Q); bitwise == __shfl(x, lb+Q).
template <int CTRL>
__device__ __forceinline__ float qbc(float x) {
  return __int_as_float(__builtin_amdgcn_update_dpp(
      0, __float_as_int(x), CTRL, 0xF, 0xF, true));
}
__device__ __forceinline__ float quadSum4(float x) {
  float s0 = qbc<0x00>(x), s1 = qbc<0x55>(x);
  float s2 = qbc<0xAA>(x), s3 = qbc<0xFF>(x);
  return ((s0 + s1) + s2) + s3;
}

// slarfg sign convention (LAPACK) — unchanged from R4-R7.
__device__ __forceinline__ void make_tau(float xn2, float alpha, float& tau,
                                         float& invs) {
  if (xn2 == 0.f) { tau = 0.f; invs = 0.f; }
  else {
    float mag = sqrtf(alpha * alpha + xn2);
    float beta = (alpha >= 0.f) ? -mag : mag;
    tau = (beta - alpha) / beta;
    invs = 1.f / (alpha - beta);
  }
}

template <bool SCALE>
__device__ __forceinline__ void publish_col(float (&a)[32], const int t,
                                            const int piv, const float invs,
                                            float* __restrict__ Vrow) {
#pragma unroll
  for (int k4 = 0; k4 < 8; ++k4) {
    float4 v4;
    float* vv = (float*)&v4;
#pragma unroll
    for (int e = 0; e < 4; ++e) {
      int k = 4 * k4 + e;
      int r = t + 4 * k;
      float nv;
      if (r > piv) {
        if (SCALE) a[k] *= invs;
        nv = a[k];
      } else nv = (r == piv) ? 1.f : 0.f;
      vv[e] = nv;
    }
    *(float4*)&Vrow[4 * k4] = v4;
  }
}

__device__ __forceinline__ void load_v(float (&vr)[32],
                                       const float* __restrict__ Vrow) {
#pragma unroll
  for (int k4 = 0; k4 < 8; ++k4) {
    float4 v4 = *(const float4*)&Vrow[4 * k4];
    vr[4 * k4 + 0] = v4.x; vr[4 * k4 + 1] = v4.y;
    vr[4 * k4 + 2] = v4.z; vr[4 * k4 + 3] = v4.w;
  }
}

// ---------------- pre-split kernels (run once per launch, write d_ws) ----------
// W_pre[m][ch] = 16KB block: hi 4096 ushorts [fg][row][8] then lo 4096.
__global__ __launch_bounds__(256) void presplit_w(const float* __restrict__ W,
                                                  unsigned short* __restrict__ Wp) {
  int id = blockIdx.x * 256 + threadIdx.x;  // (m*16+ch)*512 + fg*128 + row
  int row = id & 127;
  int fg = (id >> 7) & 3;
  int mc = id >> 9;
  int mm = mc >> 4, ch = mc & 15;
  const float* src = W + ((size_t)mm * DOUT + row) * DIN + ch * 32 + fg * 8;
  bf16x8 hi, lo;
  unsigned short* hp = (unsigned short*)&hi;
  unsigned short* lp = (unsigned short*)&lo;
#pragma unroll
  for (int e = 0; e < 8; ++e) {
    float v = src[e];
    unsigned short h = f2bf(v);
    hp[e] = h;
    lp[e] = f2bf(v - bf2f(h));
  }
  unsigned short* dst = Wp + (size_t)mc * 8192 + (fg * 128 + row) * 8;
  *(bf16x8*)dst = hi;
  *(bf16x8*)(dst + 4096) = lo;
}

// X_pre[b][ch] = 8KB block: hi 2048 ushorts [fg][col][8] (=X[kc+8fg+e][col]), lo 2048.
__global__ __launch_bounds__(256) void presplit_x(const float* __restrict__ X,
                                                  unsigned short* __restrict__ Xp) {
  int id = blockIdx.x * 256 + threadIdx.x;  // (b*16+ch)*256 + fg*64 + col
  int col = id & 63;
  int fg = (id >> 6) & 3;
  int bc = id >> 8;
  int bb = bc >> 4, ch = bc & 15;
  const float* src = X + ((size_t)bb * DIN + ch * 32 + fg * 8) * QD + col;
  bf16x8 hi, lo;
  unsigned short* hp = (unsigned short*)&hi;
  unsigned short* lp = (unsigned short*)&lo;
#pragma unroll
  for (int e = 0; e < 8; ++e) {
    float v = src[(size_t)e * QD];  // stride 64 floats; coalesced across lanes
    unsigned short h = f2bf(v);
    hp[e] = h;
    lp[e] = f2bf(v - bf2f(h));
  }
  unsigned short* dst = Xp + (size_t)bc * 4096 + (fg * 64 + col) * 8;
  *(bf16x8*)dst = hi;
  *(bf16x8*)(dst + 2048) = lo;
}

// ---------------- shared-memory layouts ----------------
union SmemPre {
  struct {
    unsigned short SW[8192];  // 16KB: Wh [fg][row][8] (4096) | Wl (4096)
    unsigned short SX[4096];  // 8KB:  Xh [fg][col][8] (2048) | Xl (2048)
  } p;
  float Buf[64][65];  // Y handoff (64-row chunks)
};
union SmemFall {
  struct {
    unsigned short Wh[DOUT][40];
    unsigned short Wl[DOUT][40];
    unsigned short Xh[QD][40];
    unsigned short Xl[QD][40];
  } g;
  float Buf[64][65];
};
template <bool PRE> struct SmemSel { using T = SmemPre; };
template <> struct SmemSel<false> { using T = SmemFall; };

// One block (256 thr = 4 waves) per matrix (m,b).
// GEMM: split-bf16 3-product MFMA; PRE mode stages pre-split fragments via
//   global_load_lds (width 16, linear LDS dest); fallback converts in-kernel.
// QR: identical to R6/R7 (1 barrier/step, DPP quad reduce, publish-ahead).
template <bool PRE>
__global__ __launch_bounds__(256, 4) void frmap_qr(
    const float* __restrict__ X, const float* __restrict__ W,
    float* __restrict__ out, const unsigned short* __restrict__ Wp,
    const unsigned short* __restrict__ Xp) {
  __shared__ __align__(16) typename SmemSel<PRE>::T U;
  __shared__ __align__(16) float Vq[2][4][36];
  __shared__ float Tau[QD];

  const int tid = threadIdx.x;
  const int l = tid & 63;                                   // lane
  const int w = __builtin_amdgcn_readfirstlane(tid >> 6);   // wave 0..3
  const int c = tid >> 2;                                   // QR column
  const int t = tid & 3;                                    // QR row class

  const int bid = blockIdx.x;  // m*256 + b
  const int m = bid >> 8;
  const int b = bid & 255;
  const float* Xb = X + (size_t)b * (DIN * QD);
  const float* Wm = W + (size_t)m * (DOUT * DIN);

  f32x4 acc[2][4];
#pragma unroll
  for (int tr = 0; tr < 2; ++tr)
#pragma unroll
    for (int tc = 0; tc < 4; ++tc)
      acc[tr][tc] = (f32x4){0.f, 0.f, 0.f, 0.f};

  const int fr = l & 15;  // row/col within 16x16 tile
  const int fg = l >> 4;  // k-group (8 bf16 each)

  if constexpr (PRE) {
    // ---------------- Phase 1 (PRE): async-staged MFMA GEMM
    const char* wbase = (const char*)Wp + (size_t)(m * 16) * 16384;
    const char* xbase = (const char*)Xp + (size_t)(b * 16) * 8192;
    for (int ch = 0; ch < 16; ++ch) {
      __syncthreads();  // prev chunk frag reads done
      const char* wsrc = wbase + ch * 16384;
      const char* xsrc = xbase + ch * 8192;
#pragma unroll
      for (int i = 0; i < 6; ++i) {
        int n = w * 6 + i;  // wave-uniform
        if (n < 16)
          gload_lds16(wsrc + n * 1024 + l * 16, (char*)U.p.SW + n * 1024);
        else
          gload_lds16(xsrc + (n - 16) * 1024 + l * 16,
                      (char*)U.p.SX + (n - 16) * 1024);
      }
      __syncthreads();  // vmcnt drained: chunk staged
#pragma unroll
      for (int tr = 0; tr < 2; ++tr) {
        int R = 32 * w + 16 * tr + fr;
        bf16x8 ah = *(const bf16x8*)&U.p.SW[(fg * 128 + R) * 8];
        bf16x8 al = *(const bf16x8*)&U.p.SW[4096 + (fg * 128 + R) * 8];
#pragma unroll
        for (int tc = 0; tc < 4; ++tc) {
          int C = 16 * tc + fr;
          bf16x8 bh = *(const bf16x8*)&U.p.SX[(fg * 64 + C) * 8];
          bf16x8 bl = *(const bf16x8*)&U.p.SX[2048 + (fg * 64 + C) * 8];
          acc[tr][tc] = __builtin_amdgcn_mfma_f32_16x16x32_bf16(ah, bh,
                                                                acc[tr][tc], 0, 0, 0);
          acc[tr][tc] = __builtin_amdgcn_mfma_f32_16x16x32_bf16(ah, bl,
                                                                acc[tr][tc], 0, 0, 0);
          acc[tr][tc] = __builtin_amdgcn_mfma_f32_16x16x32_bf16(al, bh,
                                                                acc[tr][tc], 0, 0, 0);
        }
      }
    }
  } else {
    // ---------------- Phase 1 (fallback): R7 in-kernel conversion GEMM
    for (int kc = 0; kc < DIN; kc += 32) {
      ushort4 wh[4], wl[4];
      int wrow[4], wkw[4];
#pragma unroll
      for (int i = 0; i < 4; ++i) {
        int f = 4 * tid + i;
        wrow[i] = f >> 3;
        wkw[i] = f & 7;
        float4 v = *(const float4*)(Wm + wrow[i] * DIN + kc + 4 * wkw[i]);
        float p[4] = {v.x, v.y, v.z, v.w};
        unsigned short* hp = (unsigned short*)&wh[i];
        unsigned short* lp = (unsigned short*)&wl[i];
#pragma unroll
        for (int e = 0; e < 4; ++e) {
          unsigned short hh = f2bf(p[e]);
          hp[e] = hh;
          lp[e] = f2bf(p[e] - bf2f(hh));
        }
      }
      unsigned short xh[8], xl[8];
#pragma unroll
      for (int j = 0; j < 8; ++j) {
        float xvj = Xb[(kc + w + 4 * j) * QD + l];
        unsigned short hh = f2bf(xvj);
        xh[j] = hh;
        xl[j] = f2bf(xvj - bf2f(hh));
      }
      __syncthreads();
#pragma unroll
      for (int i = 0; i < 4; ++i) {
        *(ushort4*)&U.g.Wh[wrow[i]][4 * wkw[i]] = wh[i];
        *(ushort4*)&U.g.Wl[wrow[i]][4 * wkw[i]] = wl[i];
      }
#pragma unroll
      for (int j = 0; j < 8; ++j) {
        U.g.Xh[l][w + 4 * j] = xh[j];
        U.g.Xl[l][w + 4 * j] = xl[j];
      }
      __syncthreads();
#pragma unroll
      for (int tr = 0; tr < 2; ++tr) {
        bf16x8 ah = *(const bf16x8*)&U.g.Wh[32 * w + 16 * tr + fr][8 * fg];
        bf16x8 al = *(const bf16x8*)&U.g.Wl[32 * w + 16 * tr + fr][8 * fg];
#pragma unroll
        for (int tc = 0; tc < 4; ++tc) {
          bf16x8 bh = *(const bf16x8*)&U.g.Xh[16 * tc + fr][8 * fg];
          bf16x8 bl = *(const bf16x8*)&U.g.Xl[16 * tc + fr][8 * fg];
          acc[tr][tc] = __builtin_amdgcn_mfma_f32_16x16x32_bf16(ah, bh,
                                                                acc[tr][tc], 0, 0, 0);
          acc[tr][tc] = __builtin_amdgcn_mfma_f32_16x16x32_bf16(ah, bl,
                                                                acc[tr][tc], 0, 0, 0);
          acc[tr][tc] = __builtin_amdgcn_mfma_f32_16x16x32_bf16(al, bh,
                                                                acc[tr][tc], 0, 0, 0);
        }
      }
    }
  }

  // ---------------- Phase 1.5: acc -> Buf -> QR ownership (c=tid>>2, t=tid&3)
  // C/D layout (m89-verified): col = lane&15, row = (lane>>4)*4 + reg.
  float a[32];
  __syncthreads();  // all frag reads done before Buf (union) overwrite
  if (w < 2) {      // rows 0..63
#pragma unroll
    for (int tr = 0; tr < 2; ++tr)
#pragma unroll
      for (int tc = 0; tc < 4; ++tc)
#pragma unroll
        for (int v = 0; v < 4; ++v)
          U.Buf[32 * w + 16 * tr + 4 * fg + v][16 * tc + fr] = acc[tr][tc][v];
  }
  __syncthreads();
#pragma unroll
  for (int k = 0; k < 16; ++k) a[k] = U.Buf[t + 4 * k][c];
  __syncthreads();
  if (w >= 2) {     // rows 64..127
#pragma unroll
    for (int tr = 0; tr < 2; ++tr)
#pragma unroll
      for (int tc = 0; tc < 4; ++tc)
#pragma unroll
        for (int v = 0; v < 4; ++v)
          U.Buf[32 * (w - 2) + 16 * tr + 4 * fg + v][16 * tc + fr] =
              acc[tr][tc][v];
  }
  __syncthreads();
#pragma unroll
  for (int k = 16; k < 32; ++k) a[k] = U.Buf[t + 4 * k - 64][c];

  // ---------------- prologue: quad 0 makes tau0/invs0, scales, publishes V_0
  if (c == 0) {
    float s = 0.f, myalpha = 0.f;
#pragma unroll
    for (int k = 0; k < 32; ++k) {
      int r = t + 4 * k;
      if (r > 0) s = fmaf(a[k], a[k], s);
      if (r == 0) myalpha = a[k];
    }
    float xn2 = quadSum4(s);
    float alpha = qbc<0x00>(myalpha);
    float tau, invs;
    make_tau(xn2, alpha, tau, invs);
    if (t == 0) Tau[0] = tau;
    publish_col<true>(a, t, 0, invs, &Vq[0][t][0]);
  }
  __syncthreads();  // B0: V_0 / Tau[0] visible

  // ---------------- Phase 2a: sgeqr2 (1 barrier/step, publish-ahead)
  for (int j = 0; j < QD - 1; ++j) {
    if (c > j) {
      float taul = Tau[j];
      float vr[32];
      load_v(vr, &Vq[j & 1][t][0]);
      float p = 0.f;
#pragma unroll
      for (int k = 0; k < 32; ++k) p = fmaf(vr[k], a[k], p);
      float wv = taul * quadSum4(p);
#pragma unroll
      for (int k = 0; k < 32; ++k) a[k] = fmaf(-wv, vr[k], a[k]);
      if (c == j + 1) {
        float s = 0.f, myalpha = 0.f;
#pragma unroll
        for (int k = 0; k < 32; ++k) {
          int r = t + 4 * k;
          if (r > j + 1) s = fmaf(a[k], a[k], s);
          if (r == j + 1) myalpha = a[k];  // static reg index
        }
        float xn2 = quadSum4(s);
        float alpha;
        switch ((j + 1) & 3) {
          case 0:  alpha = qbc<0x00>(myalpha); break;
          case 1:  alpha = qbc<0x55>(myalpha); break;
          case 2:  alpha = qbc<0xAA>(myalpha); break;
          default: alpha = qbc<0xFF>(myalpha); break;
        }
        float tau, invs;
        make_tau(xn2, alpha, tau, invs);
        if (t == 0) Tau[j + 1] = tau;
        publish_col<true>(a, t, j + 1, invs, &Vq[(j + 1) & 1][t][0]);
      }
    }
    __syncthreads();
  }

  __syncthreads();  // phase boundary (protect Vq[1])

  // ---------------- Phase 2b: sorg2r (1 barrier/step, publish-ahead)
  for (int i = QD - 1; i >= 0; --i) {
    if (c > i) {
      float taul = Tau[i];
      float vr[32];
      load_v(vr, &Vq[i & 1][t][0]);
      float p = 0.f;
#pragma unroll
      for (int k = 0; k < 32; ++k) p = fmaf(vr[k], a[k], p);
      float wv = taul * quadSum4(p);
#pragma unroll
      for (int k = 0; k < 32; ++k) a[k] = fmaf(-wv, vr[k], a[k]);
    } else if (c == i) {
      float taul = Tau[i];
#pragma unroll
      for (int k = 0; k < 32; ++k) {
        int r = t + 4 * k;
        float val = a[k];
        float nv;
        if (r == i) nv = 1.f - taul;
        else if (r < i) nv = 0.f;
        else nv = -taul * val;
        a[k] = nv;
      }
    } else if (c == i - 1) {
      publish_col<false>(a, t, i - 1, 0.f, &Vq[(i - 1) & 1][t][0]);
    }
    if (i) __syncthreads();
  }

  // ---------------- Phase 3: store Q
  float* O = out + (size_t)bid * (DOUT * QD);
#pragma unroll
  for (int k = 0; k < 32; ++k) O[(t + 4 * k) * QD + c] = a[k];
}

extern "C" void kernel_launch(void* const* d_in, const int* in_sizes, int n_in,
                              void* d_out, int out_size, void* d_ws, size_t ws_size,
                              hipStream_t stream) {
  const float* X = (const float*)d_in[0];   // (256, 512, 64) fp32
  const float* W = (const float*)d_in[1];   // (16, 128, 512) fp32
  float* out = (float*)d_out;               // (4096, 128, 64) fp32

  const size_t needW = (size_t)NMAPS * 16 * 16384;  // 4 MiB
  const size_t needX = (size_t)256 * 16 * 8192;     // 32 MiB
  if (ws_size >= needW + needX) {
    unsigned short* Wp = (unsigned short*)d_ws;
    unsigned short* Xp = (unsigned short*)((char*)d_ws + needW);
    presplit_w<<<512, 256, 0, stream>>>(W, Wp);
    presplit_x<<<4096, 256, 0, stream>>>(X, Xp);
    frmap_qr<true><<<NMAPS * 256, 256, 0, stream>>>(X, W, out, Wp, Xp);
  } else {
    frmap_qr<false><<<NMAPS * 256, 256, 0, stream>>>(X, W, out, nullptr, nullptr);
  }
}